// Round 18
// baseline (215.716 us; speedup 1.0000x reference)
//
#include <hip/hip_runtime.h>
#include <hip/hip_bf16.h>

typedef float f32x4 __attribute__((ext_vector_type(4)));
typedef float f32x16 __attribute__((ext_vector_type(16)));
typedef short bf16x8 __attribute__((ext_vector_type(8)));
typedef unsigned short us8 __attribute__((ext_vector_type(8)));
typedef unsigned short us4 __attribute__((ext_vector_type(4)));

__device__ __forceinline__ unsigned short f2bf(float f) {
  union { float f; unsigned u; } v; v.f = f;
  return (unsigned short)((v.u + 0x8000u) >> 16);   // round-half-up bf16
}
__device__ __forceinline__ float bf2f(unsigned short u) {
  union { unsigned u; float f; } v; v.u = ((unsigned)u) << 16;
  return v.f;
}

// ---------------------------------------------------------------------------
// Kernel 1: VmatT[b][n][p] (bf16), n = c*16+u*4+v (256), p = pi*64+pj (4096)
// ---------------------------------------------------------------------------
__global__ __launch_bounds__(256) void prep_vmat(const float* __restrict__ x,
                                                 unsigned short* __restrict__ vmatT) {
  int t = blockIdx.x * 256 + threadIdx.x;
  int pc = t & 511;
  int n  = (t >> 9) & 255;
  int b  = t >> 17;
  int c = n >> 4, u = (n >> 2) & 3, v = n & 3;
  int pi = pc >> 3;
  int pj0 = (pc & 7) << 3;
  int row = 2 * pi + u - 1;
  row = row < 0 ? 0 : (row > 127 ? 127 : row);
  const float* xr = x + ((size_t)(b * 16 + c) * 128 + row) * 128;
  us8 o;
#pragma unroll
  for (int e = 0; e < 8; ++e) {
    int col = 2 * (pj0 + e) + v - 1;
    col = col < 0 ? 0 : (col > 127 ? 127 : col);
    o[e] = f2bf(xr[col]);
  }
  *reinterpret_cast<us8*>(vmatT + (size_t)t * 8) = o;
}

// ---------------------------------------------------------------------------
// Kernel 2: A[b][q][n] = sum_p scores*VmatT via 32x32x16 MFMA.
// BQ=128, 512 thr / 8 waves: group g=wq>>2 owns K-half g (2048), wave-in-
// group wv=wq&3 owns rows qb+wv*32..+31 (one 32-row MFMA chain, acc 8x16).
// Each wave reads 32KB B-tile per iter covering 32 rows x 64 k of BOTH...
// per-CU LDS reads per unit work HALVED vs R13 (8 waves cover 128 rows x
// 128 k per iter-pair of tiles). LDS floor ~63us < HBM floor 81us.
//  - A: per-lane row l&31, k-off (l>>5)*8; 2-deep f32 staging (rE/rO, 64
//    VGPR); CONV extracts 4 bf16 frags BEFORE reload (R5 lesson).
//  - B: two independent double-buffers ldsB[g][2] (128 KB total); threads
//    t<256 stage group 0, t>=256 group 1 (8 x gload_lds 16B each); source
//    slot pre-swizzled gs=(c&7)^((c>>3)&7); read pos=(kb*2+lhi)^(l31&7)
//    (4-way bank alias tolerated; LDS still below HBM floor).
//  - per iter: CONV; STAGE_B(kt+1,buf^1); LOAD_A(kt+2); 32 MFMA;
//    vmcnt(8) leaves A(kt+2) riding the single barrier (R13 discipline).
//  - final: g=1 waves dump acc to LDS (f32), g=0 waves sum + write Amat.
//  - 32 uniform iters; wrap tails (&31) kept alive by asm.
// ---------------------------------------------------------------------------
__global__ __launch_bounds__(512, 2) void gemm_scores_vmat(
    const float* __restrict__ scores,
    const unsigned short* __restrict__ vmatT,
    unsigned short* __restrict__ Amat) {
  __shared__ unsigned short ldsB[2][2][16384];  // [group][ring][256 x 64 bf16]

  int bid = blockIdx.x;                        // 256 blocks
  int batch = bid & 7;                         // = XCD id
  int qb = (bid >> 3) << 7;                    // 32 q-blocks of 128
  const int phase = (bid >> 3) & 31;

  const int t = threadIdx.x;
  const int lane = t & 63;
  const int wq = t >> 6;
  const int g = wq >> 2;                       // K-half group
  const int wv = wq & 3;                       // 32-row slice in group
  const int l31 = lane & 31, lhi = lane >> 5;

  const size_t kbase = (size_t)g * 2048;
  // A: per-lane fragment base (row = qb+wv*32+l31, k-offset lhi*8)
  const float* aLane = scores +
      ((size_t)(batch * 4096 + qb + wv * 32 + l31)) * 4096 + kbase + lhi * 8;

  // B staging: threads 0..255 stage group 0's tile, 256..511 group 1's.
  const int st = t & 255, st_g = t >> 8;
  const unsigned short* Vb =
      vmatT + (size_t)batch * 256 * 4096 + (size_t)st_g * 2048;
  const unsigned short* bSrc[8];
#pragma unroll
  for (int i = 0; i < 8; ++i) {
    int c = st + i * 256;                      // 0..2047
    int gs = (c & 7) ^ ((c >> 3) & 7);
    bSrc[i] = Vb + (size_t)(c >> 3) * 4096 + gs * 8;
  }

  f32x16 acc[8];
#pragma unroll
  for (int nb = 0; nb < 8; ++nb)
#pragma unroll
    for (int e = 0; e < 16; ++e) acc[nb][e] = 0.f;

  f32x4 rE[8], rO[8];     // two named A sets (tile = 4 kb x 2 f32x4)
  bf16x8 fa[4];

#define SB __builtin_amdgcn_sched_barrier(0)
#define STAGE_B(kt, bufi)                                                     \
  {                                                                           \
    int kp_ = ((kt) + phase) & 31;                                            \
    _Pragma("unroll") for (int i = 0; i < 8; ++i)                             \
        __builtin_amdgcn_global_load_lds(                                     \
            (const __attribute__((address_space(1))) void*)(bSrc[i] + (size_t)kp_ * 64), \
            (__attribute__((address_space(3))) void*)&ldsB[st_g][bufi][(st + i * 256) * 8], \
            16, 0, 0);                                                        \
  }
#define LOAD_A(kt, rr)                                                        \
  {                                                                           \
    int kp_ = ((kt) + phase) & 31;                                            \
    const float* ap_ = aLane + (size_t)kp_ * 64;                              \
    rr[0] = *(const f32x4*)(ap_);                                             \
    rr[1] = *(const f32x4*)(ap_ + 4);                                         \
    rr[2] = *(const f32x4*)(ap_ + 16);                                        \
    rr[3] = *(const f32x4*)(ap_ + 20);                                        \
    rr[4] = *(const f32x4*)(ap_ + 32);                                        \
    rr[5] = *(const f32x4*)(ap_ + 36);                                        \
    rr[6] = *(const f32x4*)(ap_ + 48);                                        \
    rr[7] = *(const f32x4*)(ap_ + 52);                                        \
  }
#define CONV(rr)                                                              \
  {                                                                           \
    _Pragma("unroll") for (int kb = 0; kb < 4; ++kb)                          \
        _Pragma("unroll") for (int e = 0; e < 4; ++e) {                       \
      fa[kb][e]     = (short)f2bf(rr[2 * kb][e]);                             \
      fa[kb][e + 4] = (short)f2bf(rr[2 * kb + 1][e]);                         \
    }                                                                         \
  }
#define MFMAS(bufi)                                                           \
  {                                                                           \
    _Pragma("unroll") for (int kb = 0; kb < 4; ++kb)                          \
        _Pragma("unroll") for (int nb = 0; nb < 8; ++nb) {                    \
      int row_ = nb * 32 + l31;                                               \
      int pos_ = (kb * 2 + lhi) ^ (l31 & 7);                                  \
      bf16x8 bv = *(const bf16x8*)(&ldsB[g][bufi][0] + row_ * 64 + pos_ * 8); \
      acc[nb] = __builtin_amdgcn_mfma_f32_32x32x16_bf16(fa[kb], bv, acc[nb],  \
                                                        0, 0, 0);             \
    }                                                                         \
  }
#define BODY(b_, kt, rr)                                                      \
  {                                                                           \
    CONV(rr);                   /* extract BEFORE reload */                   \
    SB;                                                                       \
    STAGE_B((kt) + 1, (b_) ^ 1);                                              \
    SB;                                                                       \
    LOAD_A((kt) + 2, rr);                                                     \
    SB;                                                                       \
    MFMAS(b_);                                                                \
    SB;                                                                       \
    asm volatile("s_waitcnt vmcnt(8)" ::: "memory");                          \
    SB;                                                                       \
    __builtin_amdgcn_s_barrier();                                             \
    SB;                                                                       \
  }

  // ---- prologue: B(0)[8], A(0)[8], A(1)[8]; vmcnt(8) drains B0+A0.
  STAGE_B(0, 0);
  SB;
  LOAD_A(0, rE);
  SB;
  LOAD_A(1, rO);
  SB;
  asm volatile("s_waitcnt vmcnt(8)" ::: "memory");
  SB;
  __builtin_amdgcn_s_barrier();
  SB;

  // ---- main loop: 32 uniform iters, unrolled x2 (static reg-set roles)
  for (int kt = 0; kt < 32; kt += 2) {
    BODY(0, kt, rE);
    BODY(1, kt + 1, rO);
  }

  // keep tail wrap prefetches live so the vmcnt FIFO accounting stays exact
  asm volatile("" ::"v"(rE[0][0]), "v"(rE[3][0]), "v"(rE[5][0]), "v"(rE[7][0]),
               "v"(rO[0][0]), "v"(rO[3][0]), "v"(rO[5][0]), "v"(rO[7][0]));

#undef SB
#undef STAGE_B
#undef LOAD_A
#undef CONV
#undef MFMAS
#undef BODY

  // ---- cross-group K-reduction: g=1 dumps acc to LDS, g=0 sums + writes.
  __syncthreads();
  float* ldsF = reinterpret_cast<float*>(&ldsB[0][0][0]);   // 128 KB
  if (g == 1) {
#pragma unroll
    for (int nb = 0; nb < 8; ++nb)
#pragma unroll
      for (int r = 0; r < 16; ++r)
        ldsF[((wv * 128) + nb * 16 + r) * 64 + lane] = acc[nb][r];
  }
  __syncthreads();
  if (g == 0) {
    // C/D layout (32x32): col = l31, row = (r&3) + 8*(r>>2) + 4*lhi
    unsigned short* Ao =
        Amat + ((size_t)(batch * 4096 + qb + wv * 32)) * 256;
#pragma unroll
    for (int nb = 0; nb < 8; ++nb)
#pragma unroll
      for (int r = 0; r < 16; ++r) {
        float s = acc[nb][r] + ldsF[((wv * 128) + nb * 16 + r) * 64 + lane];
        int row = (r & 3) + 8 * (r >> 2) + 4 * lhi;
        Ao[(size_t)row * 256 + nb * 32 + l31] = f2bf(s);
      }
  }
}

// ---------------------------------------------------------------------------
// Kernel 3: coalesced LDS-staged epilogue (R16, proven -10.6 us).
// ---------------------------------------------------------------------------
__global__ __launch_bounds__(256) void epilogue_kernel(
    const float* __restrict__ x, const unsigned short* __restrict__ Amat,
    const float* __restrict__ alpha, float* __restrict__ out) {
  __shared__ unsigned short L[2 * 64 * 66];   // plane p, row j, col cv (c*4+v)

  int b = blockIdx.x >> 7;
  int h = blockIdx.x & 127;
  int t = threadIdx.x;

  int ihi = (h + 1) >> 1, u_hi = (h + 1) & 1;
  bool p0ok = (ihi <= 63), p1ok = (ihi >= 1);
  const unsigned short* Ab = Amat + (size_t)b * 4096 * 256;

  unsigned int* Lw = reinterpret_cast<unsigned int*>(L);
#pragma unroll
  for (int p = 0; p < 2; ++p) {
    bool ok = p ? p1ok : p0ok;
    int rbase = (p ? (ihi - 1) : ihi) * 64;
    int u = u_hi + 2 * p;
#pragma unroll
    for (int i = 0; i < 4; ++i) {
      int q = t + 256 * i;
      int j = q >> 4, c = q & 15;
      us4 ch = (us4){0, 0, 0, 0};
      if (ok)
        ch = *reinterpret_cast<const us4*>(Ab + (size_t)(rbase + j) * 256 +
                                           c * 16 + u * 4);
      int widx = (p * 4224 + j * 66 + c * 4) >> 1;
      Lw[widx]     = (unsigned int)(unsigned short)ch[0] |
                     ((unsigned int)(unsigned short)ch[1] << 16);
      Lw[widx + 1] = (unsigned int)(unsigned short)ch[2] |
                     ((unsigned int)(unsigned short)ch[3] << 16);
    }
  }
  __syncthreads();

  int w = t & 127;
  int cg = t >> 7;
  int jhi = (w + 1) >> 1, v_hi = (w + 1) & 1;
  bool vj_hi = (jhi <= 63), vj_lo = (jhi >= 1);
  float al = alpha[0] * 0.25f;

#pragma unroll
  for (int cc = 0; cc < 8; ++cc) {
    int c = cg * 8 + cc;
    float s = 0.f;
    if (vj_hi) {
      int o = jhi * 66 + c * 4 + v_hi;
      s += bf2f(L[o]) + bf2f(L[4224 + o]);
    }
    if (vj_lo) {
      int o = (jhi - 1) * 66 + c * 4 + v_hi + 2;
      s += bf2f(L[o]) + bf2f(L[4224 + o]);
    }
    size_t xi = (((size_t)b * 16 + c) * 128 + h) * 128 + w;
    out[xi] = x[xi] + al * s;
  }
}

extern "C" void kernel_launch(void* const* d_in, const int* in_sizes, int n_in,
                              void* d_out, int out_size, void* d_ws, size_t ws_size,
                              hipStream_t stream) {
  const float* x      = (const float*)d_in[0];
  const float* scores = (const float*)d_in[1];
  const float* alpha  = (const float*)d_in[2];
  float* out = (float*)d_out;

  unsigned short* vmatT = (unsigned short*)d_ws;
  unsigned short* Amat  = (unsigned short*)((char*)d_ws + (size_t)16 * 1024 * 1024);

  prep_vmat<<<4096, 256, 0, stream>>>(x, vmatT);
  gemm_scores_vmat<<<256, 512, 0, stream>>>(scores, vmatT, Amat);
  epilogue_kernel<<<1024, 256, 0, stream>>>(x, Amat, alpha, out);
}

// Round 19
// 169.132 us; speedup vs baseline: 1.2754x; 1.2754x over previous
//
#include <hip/hip_runtime.h>
#include <hip/hip_bf16.h>

typedef float f32x4 __attribute__((ext_vector_type(4)));
typedef short bf16x8 __attribute__((ext_vector_type(8)));
typedef unsigned short us8 __attribute__((ext_vector_type(8)));
typedef unsigned short us4 __attribute__((ext_vector_type(4)));

__device__ __forceinline__ unsigned short f2bf(float f) {
  union { float f; unsigned u; } v; v.f = f;
  return (unsigned short)((v.u + 0x8000u) >> 16);   // round-half-up bf16
}
__device__ __forceinline__ float bf2f(unsigned short u) {
  union { unsigned u; float f; } v; v.u = ((unsigned)u) << 16;
  return v.f;
}

// ---------------------------------------------------------------------------
// Kernel 1: VmatT[b][n][p] (bf16), n = c*16+u*4+v (256), p = pi*64+pj (4096)
// ---------------------------------------------------------------------------
__global__ __launch_bounds__(256) void prep_vmat(const float* __restrict__ x,
                                                 unsigned short* __restrict__ vmatT) {
  int t = blockIdx.x * 256 + threadIdx.x;
  int pc = t & 511;
  int n  = (t >> 9) & 255;
  int b  = t >> 17;
  int c = n >> 4, u = (n >> 2) & 3, v = n & 3;
  int pi = pc >> 3;
  int pj0 = (pc & 7) << 3;
  int row = 2 * pi + u - 1;
  row = row < 0 ? 0 : (row > 127 ? 127 : row);
  const float* xr = x + ((size_t)(b * 16 + c) * 128 + row) * 128;
  us8 o;
#pragma unroll
  for (int e = 0; e < 8; ++e) {
    int col = 2 * (pj0 + e) + v - 1;
    col = col < 0 ? 0 : (col > 127 ? 127 : col);
    o[e] = f2bf(xr[col]);
  }
  *reinterpret_cast<us8*>(vmatT + (size_t)t * 8) = o;
}

// ---------------------------------------------------------------------------
// Kernel 2: A[b][q][n] = sum_p scores[b][q][p] * VmatT[b][n][p]
// SQUARE-WAVE-TILE GEMM: BQ=128 x N=256, 8 waves as 2M x 4N (wave tile
// 64x64, acc 4x4 f32x4 = 64 VGPR). LDS reads/MFMA = 0.5 (was 1.0 in all
// M-split variants) -> per-CU per-iter: LDS-read 768 cyc vs HBM 1560 cyc:
// LDS off the critical path (was co-saturated ~1:1 -> measured 126 us).
// A goes THROUGH LDS (fp32->reg->CONV->ds_write, R3 structure) with R13's
// deep-FIFO discipline (the R3-era shallow pipeline was the old 216 us).
//  - BK=32, 128 iters, ring-4 slots of (A 8 KB + B 16 KB) = 96 KB LDS.
//  - B: global_load_lds 16B x2/thread, staged 3 tiles ahead.
//  - A: 2 x dwordx4/thread fp32 loads staged 4 tiles ahead (sets a0..a3);
//    CONV+ds_write_b64 x2 one iter ahead of consumption (slot (kt+1)&3).
//  - per iter: CONV+write; STAGE_B(kt+3)[2]; LOAD_AF(kt+4)[2]; 16 MFMA
//    (8 ds_read_b128); lgkmcnt(0); vmcnt(8) = drains {B(kt+1),A(kt+2)},
//    leaves 2 iters' loads (64 KB/CU) riding the barrier; s_barrier.
//  - swizzle (both A and B tiles, rows 64 B = 4 slots): source/write slot
//    s = g ^ ((row>>1)&3); read slot = l16 ^ ((l15>>1)&3)  [R9-verified].
//  - uniform 128 iters; wrap tails (&127) harmless (slots re-verified),
//    A-set dummies kept alive by trailing asm.
// ---------------------------------------------------------------------------
__global__ __launch_bounds__(512, 2) void gemm_scores_vmat(
    const float* __restrict__ scores,
    const unsigned short* __restrict__ vmatT,
    unsigned short* __restrict__ Amat) {
  __shared__ unsigned short lds[4][12288];  // slot: A[0..4095] | B[4096..12287]

  int bid = blockIdx.x;                      // 256 blocks = 1/CU
  int batch = bid & 7;                       // = XCD id
  int qbi = bid >> 3;                        // 0..31
  int qb = qbi << 7;
  const int phase = (qbi * 4) & 127;

  const int t = threadIdx.x;
  const int lane = t & 63;
  const int wq = t >> 6;
  const int wm = wq >> 2, wn = wq & 3;       // 2M x 4N wave grid
  const int l15 = lane & 15, l16 = lane >> 4;

  // ---- A fp32 staging addresses: chunk c = t (+512): row qb+(c>>3), 4 floats
  const float* aSrc0 =
      scores + ((size_t)(batch * 4096 + qb + (t >> 3))) * 4096 + (t & 7) * 4;
  const float* aSrc1 = aSrc0 + (size_t)64 * 4096;
  // A ds_write dest (elems, within slot A region): chunk c: row r=c>>3,
  // granule g=(c&7)>>1, half h=c&1, slot s=g^((r>>1)&3)
  const int aW = (t >> 3) * 32 + ((((t & 7) >> 1) ^ ((t >> 4) & 3)) << 3) +
                 (t & 1) * 4;                // chunk c1 = +64 rows = +2048

  // ---- B staging: chunk c = t (+512): row c>>2, granule q=c&3,
  // source slot gs = q ^ ((row>>1)&3) = (c&3) ^ ((c>>3)&3)
  const unsigned short* Vb = vmatT + (size_t)batch * 256 * 4096;
  const unsigned short* bSrc[2];
  int bDst[2];
#pragma unroll
  for (int i = 0; i < 2; ++i) {
    int c = t + i * 512;
    int gs = (c & 3) ^ ((c >> 3) & 3);
    bSrc[i] = Vb + (size_t)(c >> 2) * 4096 + gs * 8;
    bDst[i] = 4096 + c * 8;
  }

  // ---- fragment read offsets (elems within slot): swizzled slot
  const int rsw = (l16 ^ ((l15 >> 1) & 3)) << 3;
  const int aR = (wm * 64 + l15) * 32 + rsw;          // + mi*512
  const int bR = 4096 + (wn * 64 + l15) * 32 + rsw;   // + ni*512

  f32x4 acc[4][4];
#pragma unroll
  for (int mi = 0; mi < 4; ++mi)
#pragma unroll
    for (int ni = 0; ni < 4; ++ni) acc[mi][ni] = (f32x4){0.f, 0.f, 0.f, 0.f};

  f32x4 a0[2], a1[2], a2[2], a3[2];   // 4 named A fp32 sets (period 4)

#define SB __builtin_amdgcn_sched_barrier(0)
#define STAGE_B(kt, sl)                                                       \
  {                                                                           \
    int kp_ = ((kt) + phase) & 127;                                           \
    _Pragma("unroll") for (int i = 0; i < 2; ++i)                             \
        __builtin_amdgcn_global_load_lds(                                     \
            (const __attribute__((address_space(1))) void*)(bSrc[i] + (size_t)kp_ * 32), \
            (__attribute__((address_space(3))) void*)&lds[sl][bDst[i]],       \
            16, 0, 0);                                                        \
  }
#define LOAD_AF(kt, rr)                                                       \
  {                                                                           \
    int kp_ = ((kt) + phase) & 127;                                           \
    rr[0] = *(const f32x4*)(aSrc0 + (size_t)kp_ * 32);                        \
    rr[1] = *(const f32x4*)(aSrc1 + (size_t)kp_ * 32);                        \
  }
#define CONVW(rr, sl)                                                         \
  {                                                                           \
    us4 p0, p1;                                                               \
    _Pragma("unroll") for (int e = 0; e < 4; ++e) {                           \
      p0[e] = f2bf(rr[0][e]);                                                 \
      p1[e] = f2bf(rr[1][e]);                                                 \
    }                                                                         \
    *(us4*)&lds[sl][aW] = p0;                                                 \
    *(us4*)&lds[sl][aW + 2048] = p1;                                          \
  }
#define MFMAS(sl)                                                             \
  {                                                                           \
    bf16x8 af[4], bv[4];                                                      \
    _Pragma("unroll") for (int mi = 0; mi < 4; ++mi)                          \
        af[mi] = *(const bf16x8*)(&lds[sl][0] + aR + mi * 512);               \
    _Pragma("unroll") for (int ni = 0; ni < 4; ++ni)                          \
        bv[ni] = *(const bf16x8*)(&lds[sl][0] + bR + ni * 512);               \
    _Pragma("unroll") for (int mi = 0; mi < 4; ++mi)                          \
        _Pragma("unroll") for (int ni = 0; ni < 4; ++ni)                      \
            acc[mi][ni] = __builtin_amdgcn_mfma_f32_16x16x32_bf16(            \
                af[mi], bv[ni], acc[mi][ni], 0, 0, 0);                        \
  }
// iter kt: consume slot sC=kt&3; stage B(kt+3)->sS=(kt+3)&3; CONV A(kt+1)
// (set cs, loaded kt-3) -> slot sW=(kt+1)&3; load A(kt+4) -> set ls=kt&3.
#define BODY(kt, sC, sS, sW, cs, ls)                                          \
  {                                                                           \
    CONVW(cs, sW);                                                            \
    SB;                                                                       \
    STAGE_B((kt) + 3, sS);                                                    \
    SB;                                                                       \
    LOAD_AF((kt) + 4, ls);                                                    \
    SB;                                                                       \
    MFMAS(sC);                                                                \
    SB;                                                                       \
    asm volatile("s_waitcnt lgkmcnt(0)" ::: "memory");                        \
    asm volatile("s_waitcnt vmcnt(8)" ::: "memory");                          \
    SB;                                                                       \
    __builtin_amdgcn_s_barrier();                                             \
    SB;                                                                       \
  }

  // ---- prologue: A0,A1,B0 -> drain all; write A(0); issue B1,A2,B2,A3
  // leaving the steady-state 8-instr FIFO {B1,A2,B2,A3}.
  LOAD_AF(0, a0);
  SB;
  LOAD_AF(1, a1);
  SB;
  STAGE_B(0, 0);
  SB;
  asm volatile("s_waitcnt vmcnt(0)" ::: "memory");
  SB;
  CONVW(a0, 0);
  SB;
  STAGE_B(1, 1);
  SB;
  LOAD_AF(2, a2);
  SB;
  STAGE_B(2, 2);
  SB;
  LOAD_AF(3, a3);
  SB;
  asm volatile("s_waitcnt lgkmcnt(0)" ::: "memory");
  SB;
  __builtin_amdgcn_s_barrier();
  SB;

  // ---- main loop: 128 uniform iters, period-4 static roles
  for (int kt = 0; kt < 128; kt += 4) {
    BODY(kt + 0, 0, 3, 1, a1, a0);
    BODY(kt + 1, 1, 0, 2, a2, a1);
    BODY(kt + 2, 2, 1, 3, a3, a2);
    BODY(kt + 3, 3, 2, 0, a0, a3);
  }

  // keep tail wrap A-prefetches live so the vmcnt FIFO accounting is exact
  asm volatile("" ::"v"(a0[0][0]), "v"(a0[1][0]), "v"(a1[0][0]), "v"(a1[1][0]),
               "v"(a2[0][0]), "v"(a2[1][0]), "v"(a3[0][0]), "v"(a3[1][0]));

#undef SB
#undef STAGE_B
#undef LOAD_AF
#undef CONVW
#undef MFMAS
#undef BODY

  // C-write: row = qb + wm*64 + mi*16 + l16*4 + j, col = wn*64 + ni*16 + l15
  unsigned short* Ao =
      Amat + ((size_t)(batch * 4096 + qb + wm * 64)) * 256 + wn * 64;
#pragma unroll
  for (int mi = 0; mi < 4; ++mi)
#pragma unroll
    for (int ni = 0; ni < 4; ++ni)
#pragma unroll
      for (int j = 0; j < 4; ++j)
        Ao[(size_t)(mi * 16 + l16 * 4 + j) * 256 + ni * 16 + l15] =
            f2bf(acc[mi][ni][j]);
}

// ---------------------------------------------------------------------------
// Kernel 3: coalesced LDS-staged epilogue (R16, proven -10.6 us).
// ---------------------------------------------------------------------------
__global__ __launch_bounds__(256) void epilogue_kernel(
    const float* __restrict__ x, const unsigned short* __restrict__ Amat,
    const float* __restrict__ alpha, float* __restrict__ out) {
  __shared__ unsigned short L[2 * 64 * 66];   // plane p, row j, col cv (c*4+v)

  int b = blockIdx.x >> 7;
  int h = blockIdx.x & 127;
  int t = threadIdx.x;

  int ihi = (h + 1) >> 1, u_hi = (h + 1) & 1;
  bool p0ok = (ihi <= 63), p1ok = (ihi >= 1);
  const unsigned short* Ab = Amat + (size_t)b * 4096 * 256;

  unsigned int* Lw = reinterpret_cast<unsigned int*>(L);
#pragma unroll
  for (int p = 0; p < 2; ++p) {
    bool ok = p ? p1ok : p0ok;
    int rbase = (p ? (ihi - 1) : ihi) * 64;
    int u = u_hi + 2 * p;
#pragma unroll
    for (int i = 0; i < 4; ++i) {
      int q = t + 256 * i;
      int j = q >> 4, c = q & 15;
      us4 ch = (us4){0, 0, 0, 0};
      if (ok)
        ch = *reinterpret_cast<const us4*>(Ab + (size_t)(rbase + j) * 256 +
                                           c * 16 + u * 4);
      int widx = (p * 4224 + j * 66 + c * 4) >> 1;
      Lw[widx]     = (unsigned int)(unsigned short)ch[0] |
                     ((unsigned int)(unsigned short)ch[1] << 16);
      Lw[widx + 1] = (unsigned int)(unsigned short)ch[2] |
                     ((unsigned int)(unsigned short)ch[3] << 16);
    }
  }
  __syncthreads();

  int w = t & 127;
  int cg = t >> 7;
  int jhi = (w + 1) >> 1, v_hi = (w + 1) & 1;
  bool vj_hi = (jhi <= 63), vj_lo = (jhi >= 1);
  float al = alpha[0] * 0.25f;

#pragma unroll
  for (int cc = 0; cc < 8; ++cc) {
    int c = cg * 8 + cc;
    float s = 0.f;
    if (vj_hi) {
      int o = jhi * 66 + c * 4 + v_hi;
      s += bf2f(L[o]) + bf2f(L[4224 + o]);
    }
    if (vj_lo) {
      int o = (jhi - 1) * 66 + c * 4 + v_hi + 2;
      s += bf2f(L[o]) + bf2f(L[4224 + o]);
    }
    size_t xi = (((size_t)b * 16 + c) * 128 + h) * 128 + w;
    out[xi] = x[xi] + al * s;
  }
}

extern "C" void kernel_launch(void* const* d_in, const int* in_sizes, int n_in,
                              void* d_out, int out_size, void* d_ws, size_t ws_size,
                              hipStream_t stream) {
  const float* x      = (const float*)d_in[0];
  const float* scores = (const float*)d_in[1];
  const float* alpha  = (const float*)d_in[2];
  float* out = (float*)d_out;

  unsigned short* vmatT = (unsigned short*)d_ws;
  unsigned short* Amat  = (unsigned short*)((char*)d_ws + (size_t)16 * 1024 * 1024);

  prep_vmat<<<4096, 256, 0, stream>>>(x, vmatT);
  gemm_scores_vmat<<<256, 512, 0, stream>>>(scores, vmatT, Amat);
  epilogue_kernel<<<1024, 256, 0, stream>>>(x, Amat, alpha, out);
}

// Round 20
// 168.531 us; speedup vs baseline: 1.2800x; 1.0036x over previous
//
#include <hip/hip_runtime.h>
#include <hip/hip_bf16.h>

typedef float f32x4 __attribute__((ext_vector_type(4)));
typedef short bf16x8 __attribute__((ext_vector_type(8)));
typedef unsigned short us8 __attribute__((ext_vector_type(8)));
typedef unsigned short us4 __attribute__((ext_vector_type(4)));

__device__ __forceinline__ unsigned short f2bf(float f) {
  union { float f; unsigned u; } v; v.f = f;
  return (unsigned short)((v.u + 0x8000u) >> 16);   // round-half-up bf16
}
__device__ __forceinline__ float bf2f(unsigned short u) {
  union { unsigned u; float f; } v; v.u = ((unsigned)u) << 16;
  return v.f;
}

// ---------------------------------------------------------------------------
// Kernel 1: VmatT[b][n][p] (bf16), n = c*16+u*4+v (256), p = pi*64+pj (4096)
// ---------------------------------------------------------------------------
__global__ __launch_bounds__(256) void prep_vmat(const float* __restrict__ x,
                                                 unsigned short* __restrict__ vmatT) {
  int t = blockIdx.x * 256 + threadIdx.x;
  int pc = t & 511;
  int n  = (t >> 9) & 255;
  int b  = t >> 17;
  int c = n >> 4, u = (n >> 2) & 3, v = n & 3;
  int pi = pc >> 3;
  int pj0 = (pc & 7) << 3;
  int row = 2 * pi + u - 1;
  row = row < 0 ? 0 : (row > 127 ? 127 : row);
  const float* xr = x + ((size_t)(b * 16 + c) * 128 + row) * 128;
  us8 o;
#pragma unroll
  for (int e = 0; e < 8; ++e) {
    int col = 2 * (pj0 + e) + v - 1;
    col = col < 0 ? 0 : (col > 127 ? 127 : col);
    o[e] = f2bf(xr[col]);
  }
  *reinterpret_cast<us8*>(vmatT + (size_t)t * 8) = o;
}

// ---------------------------------------------------------------------------
// Kernel 2: R16 GEMM (best: 162.3 us) + ONE variable: A loads are
// NONTEMPORAL (nt, evict-first in L2). Theory: the 512-MB single-use A
// stream floods each XCD's 4-MB L2 (~0.8 TB/s/XCD), evicting the 2-MB
// L2-resident VmatT slice every few us -> B refetches from L3/HBM add the
// observed ~1.5x over the A-stream floor (R12 counter: FETCH 280 MB/GEMM).
// nt shields B residency. (R9's nt test was confounded by a mid-iteration
// vmcnt(0) bubble on the weaker R7 structure.)
// Structure unchanged: BQ=128, 8 waves M-split, BK=128, 32 iters, B ring-2
// x 64 KB (128 KB LDS), A 2-deep reg staging, vmcnt(8) single-barrier FIFO.
// ---------------------------------------------------------------------------
__global__ __launch_bounds__(512, 2) void gemm_scores_vmat(
    const float* __restrict__ scores,
    const unsigned short* __restrict__ vmatT,
    unsigned short* __restrict__ Amat) {
  __shared__ unsigned short ldsB[2][32768];   // 2 x (256 rows x 128 bf16)

  int bid = blockIdx.x;                        // 256 blocks = 1/CU
  int batch = bid & 7;                         // = XCD id
  int qb = (bid >> 3) << 7;                    // 32 q-blocks of 128
  const int phase = (bid >> 3) & 31;

  const int t = threadIdx.x;
  const int lane = t & 63;
  const int wq = t >> 6;                       // wave id 0..7 = M slice
  const int l15 = lane & 15, l16 = lane >> 4;

  // A: per-lane fragment base (row = qb + wq*16 + l15, k-offset l16*8)
  const float* aLane =
      scores + ((size_t)(batch * 4096 + qb + wq * 16 + l15)) * 4096 + l16 * 8;
  const unsigned short* Vb = vmatT + (size_t)batch * 256 * 4096;

  // B staging: 4096 chunks of 16 B / tile; thread t takes c = t + i*512.
  // row = c>>4, slot = c&15, source slot pre-swizzled gs = slot ^ (row&15).
  const unsigned short* bSrc[8];
#pragma unroll
  for (int i = 0; i < 8; ++i) {
    int c = t + i * 512;
    int gs = (c & 15) ^ ((c >> 4) & 15);
    bSrc[i] = Vb + (size_t)(c >> 4) * 4096 + gs * 8;
  }

  f32x4 acc[16];
#pragma unroll
  for (int ni = 0; ni < 16; ++ni) acc[ni] = (f32x4){0.f, 0.f, 0.f, 0.f};

  f32x4 rE[8], rO[8];     // two named A sets (tile = 4 frags = 8 f32x4)
  bf16x8 fa[4];

#define SB __builtin_amdgcn_sched_barrier(0)
#define STAGE_B(kt, bufi)                                                     \
  {                                                                           \
    int kp_ = ((kt) + phase) & 31;                                            \
    _Pragma("unroll") for (int i = 0; i < 8; ++i)                             \
        __builtin_amdgcn_global_load_lds(                                     \
            (const __attribute__((address_space(1))) void*)(bSrc[i] + (size_t)kp_ * 128), \
            (__attribute__((address_space(3))) void*)&ldsB[bufi][(t + i * 512) * 8], \
            16, 0, 0);                                                        \
  }
#define LOAD_A(kt, rr)                                                        \
  {                                                                           \
    int kp_ = ((kt) + phase) & 31;                                            \
    const float* ap_ = aLane + (size_t)kp_ * 128;                             \
    rr[0] = __builtin_nontemporal_load((const f32x4*)(ap_));                  \
    rr[1] = __builtin_nontemporal_load((const f32x4*)(ap_ + 4));              \
    rr[2] = __builtin_nontemporal_load((const f32x4*)(ap_ + 32));             \
    rr[3] = __builtin_nontemporal_load((const f32x4*)(ap_ + 36));             \
    rr[4] = __builtin_nontemporal_load((const f32x4*)(ap_ + 64));             \
    rr[5] = __builtin_nontemporal_load((const f32x4*)(ap_ + 68));             \
    rr[6] = __builtin_nontemporal_load((const f32x4*)(ap_ + 96));             \
    rr[7] = __builtin_nontemporal_load((const f32x4*)(ap_ + 100));            \
  }
#define CONV(rr)                                                              \
  {                                                                           \
    _Pragma("unroll") for (int f = 0; f < 4; ++f)                             \
        _Pragma("unroll") for (int e = 0; e < 4; ++e) {                       \
      fa[f][e]     = (short)f2bf(rr[2 * f][e]);                               \
      fa[f][e + 4] = (short)f2bf(rr[2 * f + 1][e]);                           \
    }                                                                         \
  }
#define MFMAS(bufi)                                                           \
  {                                                                           \
    _Pragma("unroll") for (int ks = 0; ks < 4; ++ks)                          \
        _Pragma("unroll") for (int ni = 0; ni < 16; ++ni) {                   \
      int pos = ((ks * 4 + l16) ^ l15) << 3;                                  \
      bf16x8 bv = *(const bf16x8*)(&ldsB[bufi][0] +                           \
                                   (ni * 16 + l15) * 128 + pos);              \
      acc[ni] = __builtin_amdgcn_mfma_f32_16x16x32_bf16(fa[ks], bv, acc[ni],  \
                                                        0, 0, 0);             \
    }                                                                         \
  }
// iter kt (buf = kt&1, A set rr): consume A(kt)+B(kt)
#define BODY(b_, kt, rr)                                                      \
  {                                                                           \
    CONV(rr);                   /* extract BEFORE reload */                   \
    SB;                                                                       \
    STAGE_B((kt) + 1, (b_) ^ 1);                                              \
    SB;                                                                       \
    LOAD_A((kt) + 2, rr);                                                     \
    SB;                                                                       \
    MFMAS(b_);                                                                \
    SB;                                                                       \
    asm volatile("s_waitcnt vmcnt(8)" ::: "memory");                          \
    SB;                                                                       \
    __builtin_amdgcn_s_barrier();                                             \
    SB;                                                                       \
  }

  // ---- prologue: B(0)[8], A(0)[8], A(1)[8]; vmcnt(8) drains B0+A0,
  // leaves A(1) in flight (steady-state entry).
  STAGE_B(0, 0);
  SB;
  LOAD_A(0, rE);
  SB;
  LOAD_A(1, rO);
  SB;
  asm volatile("s_waitcnt vmcnt(8)" ::: "memory");
  SB;
  __builtin_amdgcn_s_barrier();
  SB;

  // ---- main loop: 32 uniform iters, unrolled x2 (static reg-set roles)
  for (int kt = 0; kt < 32; kt += 2) {
    BODY(0, kt, rE);
    BODY(1, kt + 1, rO);
  }

  // keep tail wrap prefetches live so the vmcnt FIFO accounting stays exact
  asm volatile("" ::"v"(rE[0][0]), "v"(rE[3][0]), "v"(rE[5][0]), "v"(rE[7][0]),
               "v"(rO[0][0]), "v"(rO[3][0]), "v"(rO[5][0]), "v"(rO[7][0]));

#undef SB
#undef STAGE_B
#undef LOAD_A
#undef CONV
#undef MFMAS
#undef BODY

  // C-write: wave wq owns q-rows qb+wq*16..+15; row=(l16*4+j), col=l15 per ni
  unsigned short* Ao = Amat + ((size_t)(batch * 4096 + qb + wq * 16)) * 256;
#pragma unroll
  for (int ni = 0; ni < 16; ++ni)
#pragma unroll
    for (int j = 0; j < 4; ++j)
      Ao[(size_t)(l16 * 4 + j) * 256 + ni * 16 + l15] = f2bf(acc[ni][j]);
}

// ---------------------------------------------------------------------------
// Kernel 3: coalesced LDS-staged epilogue (R16, proven -10.6 us).
// ---------------------------------------------------------------------------
__global__ __launch_bounds__(256) void epilogue_kernel(
    const float* __restrict__ x, const unsigned short* __restrict__ Amat,
    const float* __restrict__ alpha, float* __restrict__ out) {
  __shared__ unsigned short L[2 * 64 * 66];   // plane p, row j, col cv (c*4+v)

  int b = blockIdx.x >> 7;
  int h = blockIdx.x & 127;
  int t = threadIdx.x;

  int ihi = (h + 1) >> 1, u_hi = (h + 1) & 1;
  bool p0ok = (ihi <= 63), p1ok = (ihi >= 1);
  const unsigned short* Ab = Amat + (size_t)b * 4096 * 256;

  unsigned int* Lw = reinterpret_cast<unsigned int*>(L);
#pragma unroll
  for (int p = 0; p < 2; ++p) {
    bool ok = p ? p1ok : p0ok;
    int rbase = (p ? (ihi - 1) : ihi) * 64;
    int u = u_hi + 2 * p;
#pragma unroll
    for (int i = 0; i < 4; ++i) {
      int q = t + 256 * i;
      int j = q >> 4, c = q & 15;
      us4 ch = (us4){0, 0, 0, 0};
      if (ok)
        ch = *reinterpret_cast<const us4*>(Ab + (size_t)(rbase + j) * 256 +
                                           c * 16 + u * 4);
      int widx = (p * 4224 + j * 66 + c * 4) >> 1;
      Lw[widx]     = (unsigned int)(unsigned short)ch[0] |
                     ((unsigned int)(unsigned short)ch[1] << 16);
      Lw[widx + 1] = (unsigned int)(unsigned short)ch[2] |
                     ((unsigned int)(unsigned short)ch[3] << 16);
    }
  }
  __syncthreads();

  int w = t & 127;
  int cg = t >> 7;
  int jhi = (w + 1) >> 1, v_hi = (w + 1) & 1;
  bool vj_hi = (jhi <= 63), vj_lo = (jhi >= 1);
  float al = alpha[0] * 0.25f;

#pragma unroll
  for (int cc = 0; cc < 8; ++cc) {
    int c = cg * 8 + cc;
    float s = 0.f;
    if (vj_hi) {
      int o = jhi * 66 + c * 4 + v_hi;
      s += bf2f(L[o]) + bf2f(L[4224 + o]);
    }
    if (vj_lo) {
      int o = (jhi - 1) * 66 + c * 4 + v_hi + 2;
      s += bf2f(L[o]) + bf2f(L[4224 + o]);
    }
    size_t xi = (((size_t)b * 16 + c) * 128 + h) * 128 + w;
    out[xi] = x[xi] + al * s;
  }
}

extern "C" void kernel_launch(void* const* d_in, const int* in_sizes, int n_in,
                              void* d_out, int out_size, void* d_ws, size_t ws_size,
                              hipStream_t stream) {
  const float* x      = (const float*)d_in[0];
  const float* scores = (const float*)d_in[1];
  const float* alpha  = (const float*)d_in[2];
  float* out = (float*)d_out;

  unsigned short* vmatT = (unsigned short*)d_ws;
  unsigned short* Amat  = (unsigned short*)((char*)d_ws + (size_t)16 * 1024 * 1024);

  prep_vmat<<<4096, 256, 0, stream>>>(x, vmatT);
  gemm_scores_vmat<<<256, 512, 0, stream>>>(scores, vmatT, Amat);
  epilogue_kernel<<<1024, 256, 0, stream>>>(x, Amat, alpha, out);
}

// Round 21
// 165.645 us; speedup vs baseline: 1.3023x; 1.0174x over previous
//
#include <hip/hip_runtime.h>
#include <hip/hip_bf16.h>

typedef float f32x4 __attribute__((ext_vector_type(4)));
typedef short bf16x8 __attribute__((ext_vector_type(8)));
typedef unsigned short us8 __attribute__((ext_vector_type(8)));
typedef unsigned short us4 __attribute__((ext_vector_type(4)));

__device__ __forceinline__ unsigned short f2bf(float f) {
  union { float f; unsigned u; } v; v.f = f;
  return (unsigned short)((v.u + 0x8000u) >> 16);   // round-half-up bf16
}
__device__ __forceinline__ float bf2f(unsigned short u) {
  union { unsigned u; float f; } v; v.u = ((unsigned)u) << 16;
  return v.f;
}

// ---------------------------------------------------------------------------
// Kernel 1: VmatT[b][n][p] (bf16), n = c*16+u*4+v (256), p = pi*64+pj (4096)
// ---------------------------------------------------------------------------
__global__ __launch_bounds__(256) void prep_vmat(const float* __restrict__ x,
                                                 unsigned short* __restrict__ vmatT) {
  int t = blockIdx.x * 256 + threadIdx.x;
  int pc = t & 511;
  int n  = (t >> 9) & 255;
  int b  = t >> 17;
  int c = n >> 4, u = (n >> 2) & 3, v = n & 3;
  int pi = pc >> 3;
  int pj0 = (pc & 7) << 3;
  int row = 2 * pi + u - 1;
  row = row < 0 ? 0 : (row > 127 ? 127 : row);
  const float* xr = x + ((size_t)(b * 16 + c) * 128 + row) * 128;
  us8 o;
#pragma unroll
  for (int e = 0; e < 8; ++e) {
    int col = 2 * (pj0 + e) + v - 1;
    col = col < 0 ? 0 : (col > 127 ? 127 : col);
    o[e] = f2bf(xr[col]);
  }
  *reinterpret_cast<us8*>(vmatT + (size_t)t * 8) = o;
}

// ---------------------------------------------------------------------------
// Kernel 2: A[b][q][n] = sum_p scores[b][q][p] * VmatT[b][n][p]
// CONTIGUOUS-RUN A STAGING. Every fragment-direct variant (R7-R20) loaded A
// with 16-B chunks at 32-B stride per instruction (fragment layout forces
// floats l16*8..+4) -> half-utilized sectors, ~4 TB/s effective. Here A is
// loaded with 16 consecutive lanes covering 256 B CONTIGUOUS per row (one
// instruction = 4 rows x 256-B runs, copy-like coalescing), staged through
// registers -> bf16 -> swizzled LDS ring-2, fragments read via ds_read_b128.
// Structure: BQ=128, 8 waves M-split, BK=64, 64 iters.
// LDS: A ring-2 x 16 KB + B ring-3 x 32 KB = 128 KB, 1 block/CU.
//  - per iter kt: CONVW(A(kt+1) regs -> Aslot (kt+1)&1);
//    STAGE_B(kt+2 -> Bslot (kt+2)%3)[4]; LOAD_A(kt+2 -> set kt&1)[4];
//    MFMAS(Aslot kt&1, Bslot kt%3); lgkmcnt(0); vmcnt(8); barrier.
//    The compiler's implicit wait at CONVW drains B(kt+1)+A(kt+1) (both one
//    full iteration old -> no stall); B(kt+2)+A(kt+2) = 64 KB/CU ride the
//    barrier (R16-proven depth).
//  - A swizzle: write slot' = ((t&15)>>1)^((t>>4)&7); read ((ks*4+l16)^
//    (l15&7)) -> 2-way banks. B: R13's gs=(c&7)^((c>>3)&7), pos0 read XOR.
//  - period-6 unroll (A sets x Aslots x Bslots), 60 + 4-body tail; wrap
//    staging (&63) lands in slots not read again; regs kept alive by asm.
// ---------------------------------------------------------------------------
__global__ __launch_bounds__(512, 2) void gemm_scores_vmat(
    const float* __restrict__ scores,
    const unsigned short* __restrict__ vmatT,
    unsigned short* __restrict__ Amat) {
  __shared__ unsigned short ldsA[2][8192];    // 2 x (128 rows x 64 bf16)
  __shared__ unsigned short ldsB[3][16384];   // 3 x (256 rows x 64 bf16)

  int bid = blockIdx.x;                        // 256 blocks = 1/CU
  int batch = bid & 7;                         // = XCD id
  int qb = (bid >> 3) << 7;                    // 32 q-blocks of 128
  const int phase = (bid >> 3) & 63;

  const int t = threadIdx.x;
  const int lane = t & 63;
  const int wq = t >> 6;                       // wave id 0..7 = M slice
  const int l15 = lane & 15, l16 = lane >> 4;

  // A global: 16 lanes/row, 256-B contiguous runs. row=(t>>4)+32i, i=0..3
  const float* aLane =
      scores + ((size_t)(batch * 4096 + qb + (t >> 4))) * 4096 + (t & 15) * 4;
  // A LDS write offset (elems, add r*64): slot'=((t&15)>>1)^((t>>4)&7)
  const int aW = ((((t & 15) >> 1) ^ ((t >> 4) & 7)) << 3) + (t & 1) * 4;

  const unsigned short* Vb = vmatT + (size_t)batch * 256 * 4096;
  const unsigned short* bSrc[4];
  int bDst[4];
#pragma unroll
  for (int i = 0; i < 4; ++i) {
    int c = t + i * 512;                       // 0..2047
    int gs = (c & 7) ^ ((c >> 3) & 7);
    bSrc[i] = Vb + (size_t)(c >> 3) * 4096 + gs * 8;
    bDst[i] = c * 8;
  }
  const int pos0 = (l16 ^ (l15 & 7)) << 3;     // B read swizzle (elems)

  f32x4 acc[16];
#pragma unroll
  for (int ni = 0; ni < 16; ++ni) acc[ni] = (f32x4){0.f, 0.f, 0.f, 0.f};

  f32x4 rE[4], rO[4];     // two named A fp32 sets (4 x 16B rows-chunks)

#define SB __builtin_amdgcn_sched_barrier(0)
#define STAGE_B(kt, sl)                                                       \
  {                                                                           \
    int kp_ = ((kt) + phase) & 63;                                            \
    _Pragma("unroll") for (int i = 0; i < 4; ++i)                             \
        __builtin_amdgcn_global_load_lds(                                     \
            (const __attribute__((address_space(1))) void*)(bSrc[i] + (size_t)kp_ * 64), \
            (__attribute__((address_space(3))) void*)&ldsB[sl][bDst[i]],      \
            16, 0, 0);                                                        \
  }
#define LOAD_A(kt, rr)                                                        \
  {                                                                           \
    int kp_ = ((kt) + phase) & 63;                                            \
    _Pragma("unroll") for (int i = 0; i < 4; ++i)                             \
        rr[i] = *(const f32x4*)(aLane + (size_t)i * 32 * 4096 +               \
                                (size_t)kp_ * 64);                            \
  }
#define CONVW(rr, sl)                                                         \
  {                                                                           \
    _Pragma("unroll") for (int i = 0; i < 4; ++i) {                           \
      us4 p;                                                                  \
      _Pragma("unroll") for (int e = 0; e < 4; ++e) p[e] = f2bf(rr[i][e]);    \
      *(us4*)&ldsA[sl][((t >> 4) + 32 * i) * 64 + aW] = p;                    \
    }                                                                         \
  }
#define MFMAS(sa, sb)                                                         \
  {                                                                           \
    _Pragma("unroll") for (int ks = 0; ks < 2; ++ks) {                        \
      bf16x8 af = *(const bf16x8*)(&ldsA[sa][0] + (wq * 16 + l15) * 64 +      \
                                   (((ks * 4 + l16) ^ (l15 & 7)) << 3));      \
      _Pragma("unroll") for (int ni = 0; ni < 16; ++ni) {                     \
        bf16x8 bv = *(const bf16x8*)(&ldsB[sb][0] + (ni * 16 + l15) * 64 +    \
                                     (pos0 ^ (ks * 32)));                     \
        acc[ni] = __builtin_amdgcn_mfma_f32_16x16x32_bf16(af, bv, acc[ni],    \
                                                          0, 0, 0);           \
      }                                                                       \
    }                                                                         \
  }
// iter kt: CONV A(kt+1)->Aslot(kt+1)&1; stage B(kt+2); load A(kt+2);
// compute (Aslot kt&1, Bslot kt%3); 64 KB rides the barrier.
#define BODY(kt, cs, aslW, sbSt, ls, aslR, sbRd)                              \
  {                                                                           \
    CONVW(cs, aslW);                                                          \
    SB;                                                                       \
    STAGE_B((kt) + 2, sbSt);                                                  \
    SB;                                                                       \
    LOAD_A((kt) + 2, ls);                                                     \
    SB;                                                                       \
    MFMAS(aslR, sbRd);                                                        \
    SB;                                                                       \
    asm volatile("s_waitcnt lgkmcnt(0)" ::: "memory");                        \
    asm volatile("s_waitcnt vmcnt(8)" ::: "memory");                          \
    SB;                                                                       \
    __builtin_amdgcn_s_barrier();                                             \
    SB;                                                                       \
  }

  // ---- prologue: A0->rE, B0->Bslot0, A1->rO; write A0; B1->Bslot1.
  LOAD_A(0, rE);
  SB;
  STAGE_B(0, 0);
  SB;
  LOAD_A(1, rO);
  SB;
  asm volatile("s_waitcnt vmcnt(8)" ::: "memory");   // A0 landed
  SB;
  CONVW(rE, 0);
  SB;
  STAGE_B(1, 1);
  SB;
  asm volatile("s_waitcnt lgkmcnt(0)" ::: "memory");
  asm volatile("s_waitcnt vmcnt(4)" ::: "memory");   // B0,A1 landed; B1 rides
  SB;
  __builtin_amdgcn_s_barrier();
  SB;

  // ---- main loop: 60 iters (10 x period-6) + 4 tail bodies
  for (int kt = 0; kt < 60; kt += 6) {
    BODY(kt + 0, rO, 1, 2, rE, 0, 0);
    BODY(kt + 1, rE, 0, 0, rO, 1, 1);
    BODY(kt + 2, rO, 1, 1, rE, 0, 2);
    BODY(kt + 3, rE, 0, 2, rO, 1, 0);
    BODY(kt + 4, rO, 1, 0, rE, 0, 1);
    BODY(kt + 5, rE, 0, 1, rO, 1, 2);
  }
  BODY(60, rO, 1, 2, rE, 0, 0);
  BODY(61, rE, 0, 0, rO, 1, 1);
  BODY(62, rO, 1, 1, rE, 0, 2);   // stages wrap (dummy), slots unread after
  BODY(63, rE, 0, 2, rO, 1, 0);

  // keep tail wrap prefetches live so the vmcnt FIFO accounting stays exact
  asm volatile("" ::"v"(rE[0][0]), "v"(rE[1][0]), "v"(rE[2][0]), "v"(rE[3][0]),
               "v"(rO[0][0]), "v"(rO[1][0]), "v"(rO[2][0]), "v"(rO[3][0]));

#undef SB
#undef STAGE_B
#undef LOAD_A
#undef CONVW
#undef MFMAS
#undef BODY

  // C-write: wave wq owns q-rows qb+wq*16..+15; row=(l16*4+j), col=l15 per ni
  unsigned short* Ao = Amat + ((size_t)(batch * 4096 + qb + wq * 16)) * 256;
#pragma unroll
  for (int ni = 0; ni < 16; ++ni)
#pragma unroll
    for (int j = 0; j < 4; ++j)
      Ao[(size_t)(l16 * 4 + j) * 256 + ni * 16 + l15] = f2bf(acc[ni][j]);
}

// ---------------------------------------------------------------------------
// Kernel 3: coalesced LDS-staged epilogue (R16, proven -10.6 us).
// ---------------------------------------------------------------------------
__global__ __launch_bounds__(256) void epilogue_kernel(
    const float* __restrict__ x, const unsigned short* __restrict__ Amat,
    const float* __restrict__ alpha, float* __restrict__ out) {
  __shared__ unsigned short L[2 * 64 * 66];   // plane p, row j, col cv (c*4+v)

  int b = blockIdx.x >> 7;
  int h = blockIdx.x & 127;
  int t = threadIdx.x;

  int ihi = (h + 1) >> 1, u_hi = (h + 1) & 1;
  bool p0ok = (ihi <= 63), p1ok = (ihi >= 1);
  const unsigned short* Ab = Amat + (size_t)b * 4096 * 256;

  unsigned int* Lw = reinterpret_cast<unsigned int*>(L);
#pragma unroll
  for (int p = 0; p < 2; ++p) {
    bool ok = p ? p1ok : p0ok;
    int rbase = (p ? (ihi - 1) : ihi) * 64;
    int u = u_hi + 2 * p;
#pragma unroll
    for (int i = 0; i < 4; ++i) {
      int q = t + 256 * i;
      int j = q >> 4, c = q & 15;
      us4 ch = (us4){0, 0, 0, 0};
      if (ok)
        ch = *reinterpret_cast<const us4*>(Ab + (size_t)(rbase + j) * 256 +
                                           c * 16 + u * 4);
      int widx = (p * 4224 + j * 66 + c * 4) >> 1;
      Lw[widx]     = (unsigned int)(unsigned short)ch[0] |
                     ((unsigned int)(unsigned short)ch[1] << 16);
      Lw[widx + 1] = (unsigned int)(unsigned short)ch[2] |
                     ((unsigned int)(unsigned short)ch[3] << 16);
    }
  }
  __syncthreads();

  int w = t & 127;
  int cg = t >> 7;
  int jhi = (w + 1) >> 1, v_hi = (w + 1) & 1;
  bool vj_hi = (jhi <= 63), vj_lo = (jhi >= 1);
  float al = alpha[0] * 0.25f;

#pragma unroll
  for (int cc = 0; cc < 8; ++cc) {
    int c = cg * 8 + cc;
    float s = 0.f;
    if (vj_hi) {
      int o = jhi * 66 + c * 4 + v_hi;
      s += bf2f(L[o]) + bf2f(L[4224 + o]);
    }
    if (vj_lo) {
      int o = (jhi - 1) * 66 + c * 4 + v_hi + 2;
      s += bf2f(L[o]) + bf2f(L[4224 + o]);
    }
    size_t xi = (((size_t)b * 16 + c) * 128 + h) * 128 + w;
    out[xi] = x[xi] + al * s;
  }
}

extern "C" void kernel_launch(void* const* d_in, const int* in_sizes, int n_in,
                              void* d_out, int out_size, void* d_ws, size_t ws_size,
                              hipStream_t stream) {
  const float* x      = (const float*)d_in[0];
  const float* scores = (const float*)d_in[1];
  const float* alpha  = (const float*)d_in[2];
  float* out = (float*)d_out;

  unsigned short* vmatT = (unsigned short*)d_ws;
  unsigned short* Amat  = (unsigned short*)((char*)d_ws + (size_t)16 * 1024 * 1024);

  prep_vmat<<<4096, 256, 0, stream>>>(x, vmatT);
  gemm_scores_vmat<<<256, 512, 0, stream>>>(scores, vmatT, Amat);
  epilogue_kernel<<<1024, 256, 0, stream>>>(x, Amat, alpha, out);
}

// Round 22
// 162.383 us; speedup vs baseline: 1.3284x; 1.0201x over previous
//
#include <hip/hip_runtime.h>
#include <hip/hip_bf16.h>

typedef float f32x4 __attribute__((ext_vector_type(4)));
typedef short bf16x8 __attribute__((ext_vector_type(8)));
typedef unsigned short us8 __attribute__((ext_vector_type(8)));
typedef unsigned short us4 __attribute__((ext_vector_type(4)));

__device__ __forceinline__ unsigned short f2bf(float f) {
  union { float f; unsigned u; } v; v.f = f;
  return (unsigned short)((v.u + 0x8000u) >> 16);   // round-half-up bf16
}
__device__ __forceinline__ float bf2f(unsigned short u) {
  union { unsigned u; float f; } v; v.u = ((unsigned)u) << 16;
  return v.f;
}

// ---------------------------------------------------------------------------
// Kernel 1: VmatT[b][n][p] (bf16), n = c*16+u*4+v (256), p = pi*64+pj (4096)
// ---------------------------------------------------------------------------
__global__ __launch_bounds__(256) void prep_vmat(const float* __restrict__ x,
                                                 unsigned short* __restrict__ vmatT) {
  int t = blockIdx.x * 256 + threadIdx.x;
  int pc = t & 511;
  int n  = (t >> 9) & 255;
  int b  = t >> 17;
  int c = n >> 4, u = (n >> 2) & 3, v = n & 3;
  int pi = pc >> 3;
  int pj0 = (pc & 7) << 3;
  int row = 2 * pi + u - 1;
  row = row < 0 ? 0 : (row > 127 ? 127 : row);
  const float* xr = x + ((size_t)(b * 16 + c) * 128 + row) * 128;
  us8 o;
#pragma unroll
  for (int e = 0; e < 8; ++e) {
    int col = 2 * (pj0 + e) + v - 1;
    col = col < 0 ? 0 : (col > 127 ? 127 : col);
    o[e] = f2bf(xr[col]);
  }
  *reinterpret_cast<us8*>(vmatT + (size_t)t * 8) = o;
}

// ---------------------------------------------------------------------------
// Kernel 2: R13/R16 deep-FIFO GEMM — BEST MEASURED (162.3 us total).
// BQ=128 (512 thr, 8 waves M-split), BK=64, 64 K-tiles, B ring-4 (128 KB
// LDS), A reg-staged 4 ahead, B staged 2 ahead, vmcnt(12) leaves 96 KB/CU
// in flight across every barrier. A-stream is pattern-limited at ~4 TB/s
// (10 orthogonal interventions null — see session log R7..R21).
// ---------------------------------------------------------------------------
__global__ __launch_bounds__(512, 2) void gemm_scores_vmat(
    const float* __restrict__ scores,
    const unsigned short* __restrict__ vmatT,
    unsigned short* __restrict__ Amat) {
  __shared__ unsigned short ldsB[4][16384];   // 4 x (256 rows x 64 bf16)

  int bid = blockIdx.x;                        // 256 blocks = 1/CU
  int batch = bid & 7;                         // = XCD id
  int qb = (bid >> 3) << 7;                    // 32 q-blocks of 128
  const int phase = ((bid >> 3) * 2) & 63;

  const int t = threadIdx.x;
  const int lane = t & 63;
  const int wq = t >> 6;                       // wave id 0..7 = M slice
  const int l15 = lane & 15, l16 = lane >> 4;

  const float* aLane =
      scores + ((size_t)(batch * 4096 + qb + wq * 16 + l15)) * 4096 + l16 * 8;
  const unsigned short* Vb = vmatT + (size_t)batch * 256 * 4096;

  const unsigned short* bSrc[4];
#pragma unroll
  for (int i = 0; i < 4; ++i) {
    int c = t + i * 512;
    int gs = (c & 7) ^ ((c >> 3) & 7);
    bSrc[i] = Vb + (size_t)(c >> 3) * 4096 + gs * 8;
  }
  const int pos0 = (l16 ^ (l15 & 7)) << 3;

  f32x4 acc[16];
#pragma unroll
  for (int ni = 0; ni < 16; ++ni) acc[ni] = (f32x4){0.f, 0.f, 0.f, 0.f};

  f32x4 r0[4], r1[4], r2[4], r3[4];
  bf16x8 fa0, fa1;

#define SB __builtin_amdgcn_sched_barrier(0)
#define STAGE_B(kt, bufi)                                                     \
  {                                                                           \
    int kp_ = ((kt) + phase) & 63;                                            \
    _Pragma("unroll") for (int i = 0; i < 4; ++i)                             \
        __builtin_amdgcn_global_load_lds(                                     \
            (const __attribute__((address_space(1))) void*)(bSrc[i] + (size_t)kp_ * 64), \
            (__attribute__((address_space(3))) void*)&ldsB[bufi][(t + i * 512) * 8], \
            16, 0, 0);                                                        \
  }
#define LOAD_A(kt, rr)                                                        \
  {                                                                           \
    int kp_ = ((kt) + phase) & 63;                                            \
    const float* ap_ = aLane + (size_t)kp_ * 64;                              \
    rr[0] = *(const f32x4*)(ap_);                                             \
    rr[1] = *(const f32x4*)(ap_ + 4);                                         \
    rr[2] = *(const f32x4*)(ap_ + 32);                                        \
    rr[3] = *(const f32x4*)(ap_ + 36);                                        \
  }
#define CONV(rr)                                                              \
  {                                                                           \
    _Pragma("unroll") for (int e = 0; e < 4; ++e) {                           \
      fa0[e] = (short)f2bf(rr[0][e]); fa0[e + 4] = (short)f2bf(rr[1][e]);     \
      fa1[e] = (short)f2bf(rr[2][e]); fa1[e + 4] = (short)f2bf(rr[3][e]);     \
    }                                                                         \
  }
#define MFMAS(bufi)                                                           \
  {                                                                           \
    _Pragma("unroll") for (int ni = 0; ni < 16; ++ni) {                       \
      bf16x8 bv = *(const bf16x8*)(&ldsB[bufi][0] +                           \
                                   (ni * 16 + l15) * 64 + pos0);              \
      acc[ni] = __builtin_amdgcn_mfma_f32_16x16x32_bf16(fa0, bv, acc[ni],     \
                                                        0, 0, 0);             \
    }                                                                         \
    _Pragma("unroll") for (int ni = 0; ni < 16; ++ni) {                       \
      bf16x8 bv = *(const bf16x8*)(&ldsB[bufi][0] +                           \
                                   (ni * 16 + l15) * 64 + (pos0 ^ 32));      \
      acc[ni] = __builtin_amdgcn_mfma_f32_16x16x32_bf16(fa1, bv, acc[ni],     \
                                                        0, 0, 0);             \
    }                                                                         \
  }
#define BODY(m, kt, rr)                                                       \
  {                                                                           \
    CONV(rr);                                                                 \
    SB;                                                                       \
    STAGE_B((kt) + 2, ((m) + 2) & 3);                                         \
    SB;                                                                       \
    LOAD_A((kt) + 4, rr);                                                     \
    SB;                                                                       \
    MFMAS(m);                                                                 \
    SB;                                                                       \
    asm volatile("s_waitcnt vmcnt(12)" ::: "memory");                         \
    SB;                                                                       \
    __builtin_amdgcn_s_barrier();                                             \
    SB;                                                                       \
  }

  STAGE_B(0, 0);
  SB;
  LOAD_A(0, r0);
  SB;
  LOAD_A(1, r1);
  SB;
  LOAD_A(2, r2);
  SB;
  STAGE_B(1, 1);
  SB;
  LOAD_A(3, r3);
  SB;
  asm volatile("s_waitcnt vmcnt(12)" ::: "memory");
  SB;
  __builtin_amdgcn_s_barrier();
  SB;

  for (int kt = 0; kt < 64; kt += 4) {
    BODY(0, kt, r0);
    BODY(1, kt + 1, r1);
    BODY(2, kt + 2, r2);
    BODY(3, kt + 3, r3);
  }

  asm volatile("" ::"v"(r0[0][0]), "v"(r1[0][0]), "v"(r2[0][0]), "v"(r3[0][0]),
               "v"(r0[3][0]), "v"(r1[3][0]), "v"(r2[3][0]), "v"(r3[3][0]));

#undef SB
#undef STAGE_B
#undef LOAD_A
#undef CONV
#undef MFMAS
#undef BODY

  unsigned short* Ao = Amat + ((size_t)(batch * 4096 + qb + wq * 16)) * 256;
#pragma unroll
  for (int ni = 0; ni < 16; ++ni)
#pragma unroll
    for (int j = 0; j < 4; ++j)
      Ao[(size_t)(l16 * 4 + j) * 256 + ni * 16 + l15] = f2bf(acc[ni][j]);
}

// ---------------------------------------------------------------------------
// Kernel 3: coalesced LDS-staged epilogue (R16, proven -10.6 us).
// ---------------------------------------------------------------------------
__global__ __launch_bounds__(256) void epilogue_kernel(
    const float* __restrict__ x, const unsigned short* __restrict__ Amat,
    const float* __restrict__ alpha, float* __restrict__ out) {
  __shared__ unsigned short L[2 * 64 * 66];   // plane p, row j, col cv (c*4+v)

  int b = blockIdx.x >> 7;
  int h = blockIdx.x & 127;
  int t = threadIdx.x;

  int ihi = (h + 1) >> 1, u_hi = (h + 1) & 1;
  bool p0ok = (ihi <= 63), p1ok = (ihi >= 1);
  const unsigned short* Ab = Amat + (size_t)b * 4096 * 256;

  unsigned int* Lw = reinterpret_cast<unsigned int*>(L);
#pragma unroll
  for (int p = 0; p < 2; ++p) {
    bool ok = p ? p1ok : p0ok;
    int rbase = (p ? (ihi - 1) : ihi) * 64;
    int u = u_hi + 2 * p;
#pragma unroll
    for (int i = 0; i < 4; ++i) {
      int q = t + 256 * i;
      int j = q >> 4, c = q & 15;
      us4 ch = (us4){0, 0, 0, 0};
      if (ok)
        ch = *reinterpret_cast<const us4*>(Ab + (size_t)(rbase + j) * 256 +
                                           c * 16 + u * 4);
      int widx = (p * 4224 + j * 66 + c * 4) >> 1;
      Lw[widx]     = (unsigned int)(unsigned short)ch[0] |
                     ((unsigned int)(unsigned short)ch[1] << 16);
      Lw[widx + 1] = (unsigned int)(unsigned short)ch[2] |
                     ((unsigned int)(unsigned short)ch[3] << 16);
    }
  }
  __syncthreads();

  int w = t & 127;
  int cg = t >> 7;
  int jhi = (w + 1) >> 1, v_hi = (w + 1) & 1;
  bool vj_hi = (jhi <= 63), vj_lo = (jhi >= 1);
  float al = alpha[0] * 0.25f;

#pragma unroll
  for (int cc = 0; cc < 8; ++cc) {
    int c = cg * 8 + cc;
    float s = 0.f;
    if (vj_hi) {
      int o = jhi * 66 + c * 4 + v_hi;
      s += bf2f(L[o]) + bf2f(L[4224 + o]);
    }
    if (vj_lo) {
      int o = (jhi - 1) * 66 + c * 4 + v_hi + 2;
      s += bf2f(L[o]) + bf2f(L[4224 + o]);
    }
    size_t xi = (((size_t)b * 16 + c) * 128 + h) * 128 + w;
    out[xi] = x[xi] + al * s;
  }
}

extern "C" void kernel_launch(void* const* d_in, const int* in_sizes, int n_in,
                              void* d_out, int out_size, void* d_ws, size_t ws_size,
                              hipStream_t stream) {
  const float* x      = (const float*)d_in[0];
  const float* scores = (const float*)d_in[1];
  const float* alpha  = (const float*)d_in[2];
  float* out = (float*)d_out;

  unsigned short* vmatT = (unsigned short*)d_ws;
  unsigned short* Amat  = (unsigned short*)((char*)d_ws + (size_t)16 * 1024 * 1024);

  prep_vmat<<<4096, 256, 0, stream>>>(x, vmatT);
  gemm_scores_vmat<<<256, 512, 0, stream>>>(scores, vmatT, Amat);
  epilogue_kernel<<<1024, 256, 0, stream>>>(x, Amat, alpha, out);
}